// Round 10
// baseline (56.423 us; speedup 1.0000x reference)
//
#include <hip/hip_runtime.h>

#define IN_F   4096
#define KSZ    16
#define LOCAL  64
#define FOLDN  4081   // (4096 - 16)/1 + 1
#define BATCH  256

#define F_TILE 32     // folds per block (8 KB contiguous per block-batch)
#define NTHR   512    // 8 waves
#define B_SPLIT 4     // blocks along batch
#define B_PER  (BATCH / B_SPLIT)  // 64 batches per block
#define XCOLS  48     // F_TILE + KSZ - 1 = 47, rounded to 48
#define XROW   68     // padded row stride (floats): 16B-aligned, rows 4 banks apart

typedef float f32x4 __attribute__((ext_vector_type(4)));

__global__ __launch_bounds__(NTHR, 4)   // 4 waves/EU = 16 waves/CU = 2 blocks/CU
void LocalLinear_kernel(const float* __restrict__ x,
                        const float* __restrict__ w,
                        const float* __restrict__ bias,
                        float* __restrict__ out) {
    // transposed x tile: xs[j][bi] = x[b0+bi][f0+j]
    __shared__ float xs[XCOLS][XROW];   // 13 KB

    // XCD swizzle: the 4 b-split sharers of each 2MB weight slice run
    // concurrently on the same XCD -> slice lands in that L2 once.
    const int lin = blockIdx.x;              // 0..511, 2 blocks/CU, all resident
    const int xcd = lin & 7;
    const int i   = lin >> 3;                // 0..63 within XCD
    const int fx  = (xcd << 4) | (i & 15);   // f-tile 0..127
    const int by  = i >> 4;                  // b-split 0..3

    const int t  = threadIdx.x;
    const int f0 = fx * F_TILE;
    const int b0 = by * B_PER;

    // ---- stage x tile (coalesced global read over j; transposed LDS write) ----
    for (int idx = t; idx < 64 * B_PER; idx += NTHR) {
        const int j  = idx & 63;          // column (fold offset), only 0..47 used
        const int bi = idx >> 6;          // batch within tile
        if (j < XCOLS) {
            const int col = f0 + j;
            xs[j][bi] = (col < IN_F) ? x[(size_t)(b0 + bi) * IN_F + col] : 0.0f;
        }
    }

    const int l4 = t & 15;    // which float4 of the 64 locals
    const int fi = t >> 4;    // 0..31 within the f tile
    const int f  = f0 + fi;
    const bool valid = (f < FOLDN);

    // ---- weight fragment in registers: w[f][k][4*l4 .. 4*l4+3], k=0..15 ----
    f32x4 wf[KSZ];
    f32x4 bv = (f32x4)(0.f);
    if (valid) {
        const f32x4* wp = (const f32x4*)(w + (size_t)f * (KSZ * LOCAL) + l4 * 4);
        #pragma unroll
        for (int k = 0; k < KSZ; ++k)
            wf[k] = wp[(size_t)k * (LOCAL / 4)];   // stride 64 floats
        bv = *(const f32x4*)(bias + (size_t)f * LOCAL + l4 * 4);
    }

    __syncthreads();

    if (!valid) return;   // no barriers after this point

    float* outp = out + ((size_t)b0 * FOLDN + f) * LOCAL + l4 * 4;
    const size_t ostride = (size_t)FOLDN * LOCAL;

    for (int bi0 = 0; bi0 < B_PER; bi0 += 4) {
        f32x4 a0 = bv, a1 = bv, a2 = bv, a3 = bv;
        #pragma unroll
        for (int k = 0; k < KSZ; ++k) {
            // one aligned b128 read: x for 4 batches at fold-column fi+k
            const f32x4 xv = *(const f32x4*)&xs[fi + k][bi0];
            a0 += xv.x * wf[k];
            a1 += xv.y * wf[k];
            a2 += xv.z * wf[k];
            a3 += xv.w * wf[k];
        }
        // cached stores: L2 write-back path (beats NT by 5%, R5 vs R6)
        float* p = outp + (size_t)bi0 * ostride;
        *(f32x4*)p = a0; p += ostride;
        *(f32x4*)p = a1; p += ostride;
        *(f32x4*)p = a2; p += ostride;
        *(f32x4*)p = a3;
    }
}

extern "C" void kernel_launch(void* const* d_in, const int* in_sizes, int n_in,
                              void* d_out, int out_size, void* d_ws, size_t ws_size,
                              hipStream_t stream) {
    const float* x    = (const float*)d_in[0];
    const float* w    = (const float*)d_in[1];
    const float* bias = (const float*)d_in[2];
    float* out = (float*)d_out;

    dim3 grid(128 * B_SPLIT);   // 512 linear, swizzled in-kernel
    dim3 block(NTHR);
    LocalLinear_kernel<<<grid, block, 0, stream>>>(x, w, bias, out);
}

// Round 11
// 54.488 us; speedup vs baseline: 1.0355x; 1.0355x over previous
//
#include <hip/hip_runtime.h>

#define IN_F   4096
#define KSZ    16
#define LOCAL  64
#define FOLDN  4081   // (4096 - 16)/1 + 1
#define BATCH  256

#define F_TILE 16     // folds per block
#define B_SPLIT 4     // blocks along batch
#define B_PER  (BATCH / B_SPLIT)  // 64 batches per block
#define XROW   68     // padded row stride (floats): 16B-aligned, rows 4 banks apart

typedef float f32x4 __attribute__((ext_vector_type(4)));

// BEST CONFIG (R6/R9, 55.0-55.5 us, ~89% of measured mixed-traffic BW ceiling):
//   - weight fragment register-resident (16 x f32x4/thread), fetched ~2x device-wide
//   - x staged transposed in LDS, b128 broadcast reads, 4 batches/iter
//   - cached (write-back) stores: beat nontemporal by 5% (R5 vs R6)
//   - 1024 blocks = 4/CU = 16 waves/CU (occupancy optimum; 4 and 32 both worse)
//   - XCD swizzle: 4 b-split sharers of each weight slice concurrent on one XCD
__global__ __launch_bounds__(256, 4)
void LocalLinear_kernel(const float* __restrict__ x,
                        const float* __restrict__ w,
                        const float* __restrict__ bias,
                        float* __restrict__ out) {
    __shared__ float xs[32][XROW];   // xs[j][bi] = x[b0+bi][f0+j]

    const int lin = blockIdx.x;          // 0..1023, all resident
    const int xcd = lin & 7;
    const int i   = lin >> 3;            // 0..127 within XCD
    const int fx  = (xcd << 5) | (i & 31);   // f-tile 0..255
    const int by  = i >> 5;                  // b-split 0..3

    const int t  = threadIdx.x;
    const int f0 = fx * F_TILE;
    const int b0 = by * B_PER;

    for (int idx = t; idx < 32 * B_PER; idx += 256) {
        const int j  = idx & 31;
        const int bi = idx >> 5;
        const int col = f0 + j;
        xs[j][bi] = (col < IN_F) ? x[(size_t)(b0 + bi) * IN_F + col] : 0.0f;
    }

    const int l4 = t & 15;
    const int fi = t >> 4;
    const int f  = f0 + fi;
    const bool valid = (f < FOLDN);

    f32x4 wf[KSZ];
    f32x4 bv = (f32x4)(0.f);
    if (valid) {
        const f32x4* wp = (const f32x4*)(w + (size_t)f * (KSZ * LOCAL) + l4 * 4);
        #pragma unroll
        for (int k = 0; k < KSZ; ++k)
            wf[k] = wp[(size_t)k * (LOCAL / 4)];
        bv = *(const f32x4*)(bias + (size_t)f * LOCAL + l4 * 4);
    }

    __syncthreads();

    if (!valid) return;

    float* outp = out + ((size_t)b0 * FOLDN + f) * LOCAL + l4 * 4;
    const size_t ostride = (size_t)FOLDN * LOCAL;

    for (int bi0 = 0; bi0 < B_PER; bi0 += 4) {
        f32x4 a0 = bv, a1 = bv, a2 = bv, a3 = bv;
        #pragma unroll
        for (int k = 0; k < KSZ; ++k) {
            const f32x4 xv = *(const f32x4*)&xs[fi + k][bi0];
            a0 += xv.x * wf[k];
            a1 += xv.y * wf[k];
            a2 += xv.z * wf[k];
            a3 += xv.w * wf[k];
        }
        float* p = outp + (size_t)bi0 * ostride;
        *(f32x4*)p = a0; p += ostride;
        *(f32x4*)p = a1; p += ostride;
        *(f32x4*)p = a2; p += ostride;
        *(f32x4*)p = a3;
    }
}

extern "C" void kernel_launch(void* const* d_in, const int* in_sizes, int n_in,
                              void* d_out, int out_size, void* d_ws, size_t ws_size,
                              hipStream_t stream) {
    const float* x    = (const float*)d_in[0];
    const float* w    = (const float*)d_in[1];
    const float* bias = (const float*)d_in[2];
    float* out = (float*)d_out;

    dim3 grid(256 * B_SPLIT);   // 1024 linear, swizzled in-kernel
    dim3 block(256);
    LocalLinear_kernel<<<grid, block, 0, stream>>>(x, w, bias, out);
}